// Round 3
// baseline (660.309 us; speedup 1.0000x reference)
//
#include <hip/hip_runtime.h>

// Round 17: M=64 per block (512 thr / 8 waves), phase-count halving.
// R16 post-mortem: launch_bounds(256,4) cap-128 + loop-carried B prefetch
// spilled x[] to scratch (WRITE 1.5->128.5MB); occupancy 42% but dur flat
// (497us) -> the bound is per-phase stall latency x phase count, which more
// waves cannot fix (barrier lockstep). This round: 64 rows/block (8 waves =
// 2 row-halves x 4 col-slabs), halving both total phase count per CU and
// weight L2 traffic per row; per-wave reg shape identical to R15's proven
// no-spill 76-VGPR config; launch_bounds(512,3) = cap 170 (no spill), LDS
// 71.7KB -> 2 blocks/CU (16 waves). Numerics identical (split-fp16
// 3-product MFMA, absmax 0.0078 PASS). fp32 fallback retained for tiny ws.

typedef __attribute__((ext_vector_type(8))) _Float16 half8;
typedef __attribute__((ext_vector_type(4))) float f32x4;

#define AS 264   // fp16 A stride (+8 pad)

#define NHALF  393216    // elements per precision plane in ws
#define OFF_WC1 0        // [2][256][256]
#define OFF_WC2 131072
#define OFF_W1  262144   // [256][256]
#define OFF_W2  327680
#define WS_NEED 1572864  // bytes = 2 planes x 393216 halves x 2B

__device__ __forceinline__ float sigm(float y) { return 1.f / (1.f + __expf(-y)); }

// ---- prep: pack weights as fp16 hi/lo planes: wsl = wsh + NHALF ----
__global__ __launch_bounds__(256) void prep(const float* __restrict__ c1w,
                                            const float* __restrict__ c2w,
                                            const float* __restrict__ w1,
                                            const float* __restrict__ w2,
                                            _Float16* __restrict__ ws) {
  int i = blockIdx.x * 256 + threadIdx.x;  // 0..131071
  {
    float v = c1w[(size_t)i * 9 + 4];
    _Float16 h = (_Float16)v;
    ws[OFF_WC1 + i] = h;
    ws[NHALF + OFF_WC1 + i] = (_Float16)(v - (float)h);
  }
  {
    float v = c2w[(size_t)i * 9 + 4];
    _Float16 h = (_Float16)v;
    ws[OFF_WC2 + i] = h;
    ws[NHALF + OFF_WC2 + i] = (_Float16)(v - (float)h);
  }
  if (i < 65536) {
    float v = w1[i];
    _Float16 h = (_Float16)v;
    ws[OFF_W1 + i] = h;
    ws[NHALF + OFF_W1 + i] = (_Float16)(v - (float)h);
    v = w2[i];
    h = (_Float16)v;
    ws[OFF_W2 + i] = h;
    ws[NHALF + OFF_W2 + i] = (_Float16)(v - (float)h);
  }
}

// ---- hi/lo split store into A planes ----
__device__ __forceinline__ void hl_store(_Float16* __restrict__ Ah,
                                         _Float16* __restrict__ Al,
                                         int idx, float v) {
  _Float16 h = (_Float16)v;
  Ah[idx] = h;
  Al[idx] = (_Float16)(v - (float)h);
}

// ---- 64x256 @ 256x256 split-fp16 MFMA (each wave: 32-row half x 64 cols):
// acc = Ahi*Whi + Ahi*Wlo + Alo*Whi (fp32 accum; lo*lo dropped, ~2^-22).
// Contains its own phase barrier: the kt=0 B batch is issued BEFORE the
// barrier (B never depends on LDS), hiding L2 latency behind the barrier
// wait and the other waves' epilogue stores. Callers must NOT sync before.
__device__ __forceinline__ void mfma_run(f32x4 acc[2][4],
    const _Float16* __restrict__ Ah, const _Float16* __restrict__ Al,
    const _Float16* __restrict__ Wh, const _Float16* __restrict__ Wl,
    int aoff, size_t boff) {
  half8 bh[4], bl[4];
  #pragma unroll
  for (int nt = 0; nt < 4; nt++) {
    bh[nt] = *(const half8*)(Wh + boff + (nt << 12));
    bl[nt] = *(const half8*)(Wl + boff + (nt << 12));
  }
  #pragma unroll
  for (int mt = 0; mt < 2; mt++)
    #pragma unroll
    for (int nt = 0; nt < 4; nt++)
      acc[mt][nt] = (f32x4){0.f, 0.f, 0.f, 0.f};
  __syncthreads();
  #pragma unroll
  for (int kt = 0; kt < 8; kt++) {
    half8 ah0 = *(const half8*)(Ah + aoff + kt * 32);
    half8 ah1 = *(const half8*)(Ah + aoff + 16 * AS + kt * 32);
    half8 al0 = *(const half8*)(Al + aoff + kt * 32);
    half8 al1 = *(const half8*)(Al + aoff + 16 * AS + kt * 32);
    #pragma unroll
    for (int nt = 0; nt < 4; nt++) {
      acc[0][nt] = __builtin_amdgcn_mfma_f32_16x16x32_f16(ah0, bh[nt], acc[0][nt], 0, 0, 0);
      acc[1][nt] = __builtin_amdgcn_mfma_f32_16x16x32_f16(ah1, bh[nt], acc[1][nt], 0, 0, 0);
      acc[0][nt] = __builtin_amdgcn_mfma_f32_16x16x32_f16(ah0, bl[nt], acc[0][nt], 0, 0, 0);
      acc[1][nt] = __builtin_amdgcn_mfma_f32_16x16x32_f16(ah1, bl[nt], acc[1][nt], 0, 0, 0);
      acc[0][nt] = __builtin_amdgcn_mfma_f32_16x16x32_f16(al0, bh[nt], acc[0][nt], 0, 0, 0);
      acc[1][nt] = __builtin_amdgcn_mfma_f32_16x16x32_f16(al1, bh[nt], acc[1][nt], 0, 0, 0);
    }
    if (kt < 7) {
      #pragma unroll
      for (int nt = 0; nt < 4; nt++) {
        bh[nt] = *(const half8*)(Wh + boff + (nt << 12) + (kt + 1) * 32);
        bl[nt] = *(const half8*)(Wl + boff + (nt << 12) + (kt + 1) * 32);
      }
    }
  }
}

// ---- GN(32 groups x 8 chans)+SiLU from residual regs (C-layout) -> A ----
// Row r = rh + 16mt + 4quad + rg; chan n = nb + 16nt + col. The 8 channels
// of a group live on the 8 col-lanes sharing bits 3..5 -> shfl_xor 1/2/4.
__device__ __forceinline__ void gn_x_to_A(const float x[2][4][4],
    const float* __restrict__ gnw, const float* __restrict__ gnb,
    int col, int quad, int nb, int rh,
    _Float16* __restrict__ Ah, _Float16* __restrict__ Al) {
  #pragma unroll
  for (int nt = 0; nt < 4; nt++) {
    int n = nb + (nt << 4) + col;
    float gwv = gnw[n], gbv = gnb[n];
    #pragma unroll
    for (int mt = 0; mt < 2; mt++) {
      #pragma unroll
      for (int rg = 0; rg < 4; rg++) {
        float v = x[mt][nt][rg];
        float s = v, q = v * v;
        s += __shfl_xor(s, 1); q += __shfl_xor(q, 1);
        s += __shfl_xor(s, 2); q += __shfl_xor(q, 2);
        s += __shfl_xor(s, 4); q += __shfl_xor(q, 4);
        float mu = s * 0.125f;
        float rs = rsqrtf(q * 0.125f - mu * mu + 1e-5f);
        float y = (v - mu) * rs * gwv + gbv;
        float sv = y * sigm(y);
        hl_store(Ah, Al, (rh + (mt << 4) + (quad << 2) + rg) * AS + n, sv);
      }
    }
  }
}

// ---- (acc + bias) -> GN+SiLU -> A, all in registers ----
__device__ __forceinline__ void epi_gn_to_A(const f32x4 acc[2][4],
    const float* __restrict__ bias,
    const float* __restrict__ gnw, const float* __restrict__ gnb,
    int col, int quad, int nb, int rh,
    _Float16* __restrict__ Ah, _Float16* __restrict__ Al) {
  #pragma unroll
  for (int nt = 0; nt < 4; nt++) {
    int n = nb + (nt << 4) + col;
    float bv = bias[n];
    float gwv = gnw[n], gbv = gnb[n];
    #pragma unroll
    for (int mt = 0; mt < 2; mt++) {
      #pragma unroll
      for (int rg = 0; rg < 4; rg++) {
        float v = acc[mt][nt][rg] + bv;
        float s = v, q = v * v;
        s += __shfl_xor(s, 1); q += __shfl_xor(q, 1);
        s += __shfl_xor(s, 2); q += __shfl_xor(q, 2);
        s += __shfl_xor(s, 4); q += __shfl_xor(q, 4);
        float mu = s * 0.125f;
        float rs = rsqrtf(q * 0.125f - mu * mu + 1e-5f);
        float y = (v - mu) * rs * gwv + gbv;
        float sv = y * sigm(y);
        hl_store(Ah, Al, (rh + (mt << 4) + (quad << 2) + rg) * AS + n, sv);
      }
    }
  }
}

// ---- relu(acc + bias) -> A ----
__device__ __forceinline__ void epi_relu_to_A(const f32x4 acc[2][4],
    const float* __restrict__ bias, int col, int quad, int nb, int rh,
    _Float16* __restrict__ Ah, _Float16* __restrict__ Al) {
  #pragma unroll
  for (int nt = 0; nt < 4; nt++) {
    int n = nb + (nt << 4) + col;
    float bv = bias[n];
    #pragma unroll
    for (int mt = 0; mt < 2; mt++)
      #pragma unroll
      for (int rg = 0; rg < 4; rg++)
        hl_store(Ah, Al, (rh + (mt << 4) + (quad << 2) + rg) * AS + n,
                 fmaxf(acc[mt][nt][rg] + bv, 0.f));
  }
}

__global__ __launch_bounds__(512, 3) void fused_mfma(
    const float* __restrict__ gimage, const int* __restrict__ pts,
    const float* __restrict__ gn1w, const float* __restrict__ gn1b,
    const float* __restrict__ c1b,
    const float* __restrict__ gn2w, const float* __restrict__ gn2b,
    const float* __restrict__ c2b,
    const float* __restrict__ clsw, const float* __restrict__ clsb,
    const float* __restrict__ b1, const float* __restrict__ b2,
    const float* __restrict__ w3, const float* __restrict__ b3,
    const _Float16* __restrict__ ws, float* __restrict__ out) {
  __shared__ _Float16 Ah[64 * AS];    // activation hi (64 rows)
  __shared__ _Float16 Al[64 * AS];    // activation lo
  __shared__ float red[8][32][4];     // head reduction scratch (per-wave)

  const int t = threadIdx.x;          // 0..511
  const int w = t >> 6;               // 0..7
  const int lane = t & 63;
  const int col = lane & 15;
  const int quad = lane >> 4;
  const int nb = (w & 3) << 6;        // wave's 64-col slab
  const int rh = (w >> 2) << 5;       // wave's 32-row half base
  const int row0 = blockIdx.x << 6;   // 64 rows per block
  const int rbase = quad << 2;

  const int aoff = (rh + col) * AS + (quad << 3);
  const size_t boff = (((size_t)(nb + col)) << 8) + (quad << 3);
  const _Float16* wsl = ws + NHALF;

  // ---- gather residual X directly into C-layout registers ----
  float x[2][4][4];
  {
    int lin[2][4];
    #pragma unroll
    for (int mt = 0; mt < 2; mt++)
      #pragma unroll
      for (int rg = 0; rg < 4; rg++) {
        int grow = row0 + rh + (mt << 4) + rbase + rg;
        int p0 = pts[2 * grow], p1 = pts[2 * grow + 1];
        lin[mt][rg] = ((p0 >> 3) << 5) + (p1 >> 3);
      }
    const float* gbase = gimage + (((size_t)((row0 >> 11) << 8)) << 10);
    #pragma unroll
    for (int nt = 0; nt < 4; nt++) {
      const float* gc = gbase + (((size_t)(nb + (nt << 4) + col)) << 10);
      #pragma unroll
      for (int mt = 0; mt < 2; mt++)
        #pragma unroll
        for (int rg = 0; rg < 4; rg++)
          x[mt][nt][rg] = gc[lin[mt][rg]];
    }
  }

  f32x4 acc[2][4];

  // ---- 2x ResBlock ----
  #pragma unroll 1
  for (int rb = 0; rb < 2; rb++) {
    gn_x_to_A(x, gn1w + (rb << 8), gn1b + (rb << 8), col, quad, nb, rh, Ah, Al);
    mfma_run(acc, Ah, Al, ws + OFF_WC1 + (rb << 16), wsl + OFF_WC1 + (rb << 16),
             aoff, boff);
    __syncthreads();
    epi_gn_to_A(acc, c1b + (rb << 8), gn2w + (rb << 8), gn2b + (rb << 8),
                col, quad, nb, rh, Ah, Al);
    mfma_run(acc, Ah, Al, ws + OFF_WC2 + (rb << 16), wsl + OFF_WC2 + (rb << 16),
             aoff, boff);
    __syncthreads();
    #pragma unroll
    for (int nt = 0; nt < 4; nt++) {
      float bv = c2b[(rb << 8) + nb + (nt << 4) + col];
      #pragma unroll
      for (int mt = 0; mt < 2; mt++)
        #pragma unroll
        for (int rg = 0; rg < 4; rg++)
          x[mt][nt][rg] += acc[mt][nt][rg] + bv;
    }
  }

  // ---- A = hl(x) for the MLP; cls partials from x (regs) ----
  #pragma unroll
  for (int nt = 0; nt < 4; nt++) {
    int n = nb + (nt << 4) + col;
    #pragma unroll
    for (int mt = 0; mt < 2; mt++)
      #pragma unroll
      for (int rg = 0; rg < 4; rg++)
        hl_store(Ah, Al, (rh + (mt << 4) + rbase + rg) * AS + n, x[mt][nt][rg]);
  }
  {
    float pc[2][2][4];
    #pragma unroll
    for (int j = 0; j < 2; j++) {
      #pragma unroll
      for (int mt = 0; mt < 2; mt++)
        #pragma unroll
        for (int rg = 0; rg < 4; rg++)
          pc[j][mt][rg] = 0.f;
      #pragma unroll
      for (int nt = 0; nt < 4; nt++) {
        float wv = clsw[(j << 8) + nb + (nt << 4) + col];
        #pragma unroll
        for (int mt = 0; mt < 2; mt++)
          #pragma unroll
          for (int rg = 0; rg < 4; rg++)
            pc[j][mt][rg] += x[mt][nt][rg] * wv;
      }
    }
    #pragma unroll
    for (int j = 0; j < 2; j++)
      #pragma unroll
      for (int mt = 0; mt < 2; mt++)
        #pragma unroll
        for (int rg = 0; rg < 4; rg++) {
          float p = pc[j][mt][rg];
          p += __shfl_xor(p, 1);
          p += __shfl_xor(p, 2);
          p += __shfl_xor(p, 4);
          p += __shfl_xor(p, 8);
          if (col == 0) red[w][(mt << 4) + rbase + rg][j] = p;
        }
  }

  // ---- MLP gemm1 (w1); cls finalize rides alongside ----
  mfma_run(acc, Ah, Al, ws + OFF_W1, wsl + OFF_W1, aoff, boff);
  if (t < 128) {
    int r = t >> 1, j = t & 1;
    int h = (r >> 5) << 2, lr = r & 31;
    out[((size_t)(row0 + r) << 1) + j] =
        clsb[j] + red[h][lr][j] + red[h + 1][lr][j] + red[h + 2][lr][j] +
        red[h + 3][lr][j];
  }
  __syncthreads();
  epi_relu_to_A(acc, b1, col, quad, nb, rh, Ah, Al);

  // ---- MLP gemm2 (w2) -> relu -> w3 partials in regs ----
  mfma_run(acc, Ah, Al, ws + OFF_W2, wsl + OFF_W2, aoff, boff);
  __syncthreads();
  {
    float pb[4][2][4];
    #pragma unroll
    for (int j = 0; j < 4; j++)
      #pragma unroll
      for (int mt = 0; mt < 2; mt++)
        #pragma unroll
        for (int rg = 0; rg < 4; rg++)
          pb[j][mt][rg] = 0.f;
    #pragma unroll
    for (int nt = 0; nt < 4; nt++) {
      int n = nb + (nt << 4) + col;
      float bv = b2[n];
      float w0 = w3[n], w1v = w3[256 + n], w2v = w3[512 + n], w3v = w3[768 + n];
      #pragma unroll
      for (int mt = 0; mt < 2; mt++)
        #pragma unroll
        for (int rg = 0; rg < 4; rg++) {
          float v = fmaxf(acc[mt][nt][rg] + bv, 0.f);
          pb[0][mt][rg] += v * w0;
          pb[1][mt][rg] += v * w1v;
          pb[2][mt][rg] += v * w2v;
          pb[3][mt][rg] += v * w3v;
        }
    }
    #pragma unroll
    for (int j = 0; j < 4; j++)
      #pragma unroll
      for (int mt = 0; mt < 2; mt++)
        #pragma unroll
        for (int rg = 0; rg < 4; rg++) {
          float p = pb[j][mt][rg];
          p += __shfl_xor(p, 1);
          p += __shfl_xor(p, 2);
          p += __shfl_xor(p, 4);
          p += __shfl_xor(p, 8);
          if (col == 0) red[w][(mt << 4) + rbase + rg][j] = p;
        }
  }
  __syncthreads();
  if (t < 256) {
    int r = t >> 2, j = t & 3;
    int h = (r >> 5) << 2, lr = r & 31;
    float s = b3[j] + red[h][lr][j] + red[h + 1][lr][j] + red[h + 2][lr][j] +
              red[h + 3][lr][j];
    out[131072 + ((size_t)(row0 + r) << 2) + j] = sigm(s);
  }
}

// ================= fp32 fallback (R11, proven) for tiny ws =================
#define LS 260
template <int EPI, bool CONV>
__device__ __forceinline__ void gemm_f32(const float* __restrict__ src,
                                         const float* __restrict__ W,
                                         const float* __restrict__ bias,
                                         float* __restrict__ dst,
                                         float* __restrict__ X) {
  const int n = threadIdx.x;
  float acc[32];
  #pragma unroll
  for (int r = 0; r < 32; r++) acc[r] = 0.f;
  #pragma unroll 1
  for (int k = 0; k < 256; k += 8) {
    float w[8];
    if (CONV) {
      #pragma unroll
      for (int j = 0; j < 8; j++) w[j] = W[(size_t)((n << 8) + k + j) * 9 + 4];
    } else {
      f32x4 wa = *(const f32x4*)(W + (n << 8) + k);
      f32x4 wb = *(const f32x4*)(W + (n << 8) + k + 4);
      w[0] = wa[0]; w[1] = wa[1]; w[2] = wa[2]; w[3] = wa[3];
      w[4] = wb[0]; w[5] = wb[1]; w[6] = wb[2]; w[7] = wb[3];
    }
    #pragma unroll
    for (int r = 0; r < 32; r++) {
      const float* xr = src + r * LS + k;
      f32x4 a0 = *(const f32x4*)xr, a1 = *(const f32x4*)(xr + 4);
      acc[r] += a0[0] * w[0] + a0[1] * w[1] + a0[2] * w[2] + a0[3] * w[3]
              + a1[0] * w[4] + a1[1] * w[5] + a1[2] * w[6] + a1[3] * w[7];
    }
  }
  float bv = bias[n];
  #pragma unroll
  for (int r = 0; r < 32; r++) {
    float v = acc[r] + bv;
    if (EPI == 0) dst[r * LS + n] = v;
    else if (EPI == 1) X[r * LS + n] += v;
    else dst[r * LS + n] = fmaxf(v, 0.f);
  }
}
__device__ __forceinline__ void gn_silu32(const float* __restrict__ src,
                                          float* __restrict__ dst,
                                          const float* __restrict__ gw,
                                          const float* __restrict__ gb, int t) {
  #pragma unroll
  for (int i = 0; i < 4; i++) {
    int task = (i << 8) + t;
    int r = task >> 5, g = task & 31;
    const float* x = src + r * LS + (g << 3);
    f32x4 x0 = *(const f32x4*)x, x1 = *(const f32x4*)(x + 4);
    float xx[8] = {x0[0], x0[1], x0[2], x0[3], x1[0], x1[1], x1[2], x1[3]};
    float s = 0.f, q = 0.f;
    #pragma unroll
    for (int j = 0; j < 8; j++) { s += xx[j]; q += xx[j] * xx[j]; }
    float mu = s * 0.125f;
    float rs = rsqrtf(q * 0.125f - mu * mu + 1e-5f);
    const float* w = gw + (g << 3);
    const float* b = gb + (g << 3);
    float* d = dst + r * LS + (g << 3);
    #pragma unroll
    for (int j = 0; j < 8; j++) {
      float y = (xx[j] - mu) * rs * w[j] + b[j];
      d[j] = y * sigm(y);
    }
  }
}
__global__ __launch_bounds__(256, 1) void fused_all(
    const float* __restrict__ gimage, const int* __restrict__ pts,
    const float* __restrict__ gn1w, const float* __restrict__ gn1b,
    const float* __restrict__ c1w, const float* __restrict__ c1b,
    const float* __restrict__ gn2w, const float* __restrict__ gn2b,
    const float* __restrict__ c2w, const float* __restrict__ c2b,
    const float* __restrict__ clsw, const float* __restrict__ clsb,
    const float* __restrict__ w1, const float* __restrict__ b1,
    const float* __restrict__ w2, const float* __restrict__ b2,
    const float* __restrict__ w3, const float* __restrict__ b3,
    float* __restrict__ out) {
  __shared__ float X[32 * LS];
  __shared__ float A[32 * LS];
  __shared__ float H[32 * LS];
  const int t = threadIdx.x;
  const int row0 = blockIdx.x << 5;
  {
    int r = t >> 3;
    int c0 = (t & 7) << 5;
    int grow = row0 + r;
    int p0 = pts[2 * grow], p1 = pts[2 * grow + 1];
    int lin = ((p0 >> 3) << 5) + (p1 >> 3);
    int b = grow >> 11;
    const float* src = gimage + (((size_t)((b << 8) + c0)) << 10) + lin;
    #pragma unroll
    for (int c = 0; c < 32; c++) X[r * LS + c0 + c] = src[(size_t)c << 10];
  }
  __syncthreads();
  #pragma unroll 1
  for (int rb = 0; rb < 2; rb++) {
    gn_silu32(X, A, gn1w + (rb << 8), gn1b + (rb << 8), t);
    __syncthreads();
    gemm_f32<0, true>(A, c1w + rb * 589824, c1b + (rb << 8), H, nullptr);
    __syncthreads();
    gn_silu32(H, A, gn2w + (rb << 8), gn2b + (rb << 8), t);
    __syncthreads();
    gemm_f32<1, true>(A, c2w + rb * 589824, c2b + (rb << 8), nullptr, X);
    __syncthreads();
  }
  if (t < 64) {
    int r = t >> 1, j = t & 1;
    float s = clsb[j];
    const float* w = clsw + (j << 8);
    const float* x = X + r * LS;
    #pragma unroll 1
    for (int k = 0; k < 256; k += 4) {
      f32x4 wv = *(const f32x4*)(w + k);
      f32x4 xv = *(const f32x4*)(x + k);
      s += xv[0] * wv[0] + xv[1] * wv[1] + xv[2] * wv[2] + xv[3] * wv[3];
    }
    out[((size_t)(row0 + r) << 1) + j] = s;
  }
  gemm_f32<2, false>(X, w1, b1, H, nullptr);
  __syncthreads();
  gemm_f32<2, false>(H, w2, b2, A, nullptr);
  __syncthreads();
  if (t < 128) {
    int r = t >> 2, j = t & 3;
    float s = b3[j];
    const float* w = w3 + (j << 8);
    const float* x = A + r * LS;
    #pragma unroll 1
    for (int k = 0; k < 256; k += 4) {
      f32x4 wv = *(const f32x4*)(w + k);
      f32x4 xv = *(const f32x4*)(x + k);
      s += xv[0] * wv[0] + xv[1] * wv[1] + xv[2] * wv[2] + xv[3] * wv[3];
    }
    out[131072 + ((size_t)(row0 + r) << 2) + j] = sigm(s);
  }
}

extern "C" void kernel_launch(void* const* d_in, const int* in_sizes, int n_in,
                              void* d_out, int out_size, void* d_ws, size_t ws_size,
                              hipStream_t stream) {
  const float* gimage = (const float*)d_in[0];
  const int* pts = (const int*)d_in[1];
  const float* gn1w = (const float*)d_in[2];
  const float* gn1b = (const float*)d_in[3];
  const float* c1w = (const float*)d_in[4];
  const float* c1b = (const float*)d_in[5];
  const float* gn2w = (const float*)d_in[6];
  const float* gn2b = (const float*)d_in[7];
  const float* c2w = (const float*)d_in[8];
  const float* c2b = (const float*)d_in[9];
  const float* clsw = (const float*)d_in[10];
  const float* clsb = (const float*)d_in[11];
  const float* w1 = (const float*)d_in[12];
  const float* b1 = (const float*)d_in[13];
  const float* w2 = (const float*)d_in[14];
  const float* b2 = (const float*)d_in[15];
  const float* w3 = (const float*)d_in[16];
  const float* b3 = (const float*)d_in[17];

  if (ws_size >= (size_t)WS_NEED) {
    _Float16* ws = (_Float16*)d_ws;
    prep<<<512, 256, 0, stream>>>(c1w, c2w, w1, w2, ws);
    fused_mfma<<<1024, 512, 0, stream>>>(gimage, pts, gn1w, gn1b, c1b,
                                         gn2w, gn2b, c2b, clsw, clsb,
                                         b1, b2, w3, b3, ws, (float*)d_out);
  } else {
    fused_all<<<2048, 256, 0, stream>>>(gimage, pts, gn1w, gn1b, c1w, c1b,
                                        gn2w, gn2b, c2w, c2b, clsw, clsb,
                                        w1, b1, w2, b2, w3, b3, (float*)d_out);
  }
}

// Round 4
// 649.103 us; speedup vs baseline: 1.0173x; 1.0173x over previous
//
#include <hip/hip_runtime.h>

// Round 18: non-temporal gather to stop L2 weight-thrash.
// R17 post-mortem: M=64 regressed (598us steady, occ 24%) -> phase-count
// theory dead. Revised theory: 3 GB/dispatch of B-operand re-reads miss L2
// because the scattered image gather (use-once data) continuously evicts
// the 1.5 MB weight set from each XCD's 4 MB L2 -> B served at L3
// latency/BW (~300-400us of the ~500us). Fix: __builtin_nontemporal_load
// on gather (evict-first lines), back to R15 geometry (M=32, 256thr, LDS
// 35840, 4 blk/CU), launch_bounds(256,3) so x[]/acc[] stay in regs (R16's
// cap-128 scratch disaster: WRITE 128MB), keep R16 pre-barrier B preload.
// Numerics identical (split-fp16 3-product MFMA, absmax 0.0078 PASS).
// fp32 fallback (R11, proven) retained for tiny ws.

typedef __attribute__((ext_vector_type(8))) _Float16 half8;
typedef __attribute__((ext_vector_type(4))) float f32x4;

#define AS 264   // fp16 A stride (+8 pad)

#define NHALF  393216    // elements per precision plane in ws
#define OFF_WC1 0        // [2][256][256]
#define OFF_WC2 131072
#define OFF_W1  262144   // [256][256]
#define OFF_W2  327680
#define WS_NEED 1572864  // bytes = 2 planes x 393216 halves x 2B

__device__ __forceinline__ float sigm(float y) { return 1.f / (1.f + __expf(-y)); }

// ---- prep: pack weights as fp16 hi/lo planes: wsl = wsh + NHALF ----
__global__ __launch_bounds__(256) void prep(const float* __restrict__ c1w,
                                            const float* __restrict__ c2w,
                                            const float* __restrict__ w1,
                                            const float* __restrict__ w2,
                                            _Float16* __restrict__ ws) {
  int i = blockIdx.x * 256 + threadIdx.x;  // 0..131071
  {
    float v = c1w[(size_t)i * 9 + 4];
    _Float16 h = (_Float16)v;
    ws[OFF_WC1 + i] = h;
    ws[NHALF + OFF_WC1 + i] = (_Float16)(v - (float)h);
  }
  {
    float v = c2w[(size_t)i * 9 + 4];
    _Float16 h = (_Float16)v;
    ws[OFF_WC2 + i] = h;
    ws[NHALF + OFF_WC2 + i] = (_Float16)(v - (float)h);
  }
  if (i < 65536) {
    float v = w1[i];
    _Float16 h = (_Float16)v;
    ws[OFF_W1 + i] = h;
    ws[NHALF + OFF_W1 + i] = (_Float16)(v - (float)h);
    v = w2[i];
    h = (_Float16)v;
    ws[OFF_W2 + i] = h;
    ws[NHALF + OFF_W2 + i] = (_Float16)(v - (float)h);
  }
}

// ---- hi/lo split store into A planes ----
__device__ __forceinline__ void hl_store(_Float16* __restrict__ Ah,
                                         _Float16* __restrict__ Al,
                                         int idx, float v) {
  _Float16 h = (_Float16)v;
  Ah[idx] = h;
  Al[idx] = (_Float16)(v - (float)h);
}

// ---- 32x256 @ 256x256 split-fp16 MFMA: acc = Ahi*Whi + Ahi*Wlo + Alo*Whi.
// Contains its own phase barrier: the kt=0 B batch is issued BEFORE the
// barrier (B never depends on LDS), hiding L2 latency behind the barrier
// wait and the other waves' epilogue stores. Callers must NOT sync before.
__device__ __forceinline__ void mfma_run(f32x4 acc[2][4],
    const _Float16* __restrict__ Ah, const _Float16* __restrict__ Al,
    const _Float16* __restrict__ Wh, const _Float16* __restrict__ Wl,
    int aoff, size_t boff) {
  half8 bh[4], bl[4];
  #pragma unroll
  for (int nt = 0; nt < 4; nt++) {
    bh[nt] = *(const half8*)(Wh + boff + (nt << 12));
    bl[nt] = *(const half8*)(Wl + boff + (nt << 12));
  }
  #pragma unroll
  for (int mt = 0; mt < 2; mt++)
    #pragma unroll
    for (int nt = 0; nt < 4; nt++)
      acc[mt][nt] = (f32x4){0.f, 0.f, 0.f, 0.f};
  __syncthreads();
  #pragma unroll
  for (int kt = 0; kt < 8; kt++) {
    half8 ah0 = *(const half8*)(Ah + aoff + kt * 32);
    half8 ah1 = *(const half8*)(Ah + aoff + 16 * AS + kt * 32);
    half8 al0 = *(const half8*)(Al + aoff + kt * 32);
    half8 al1 = *(const half8*)(Al + aoff + 16 * AS + kt * 32);
    #pragma unroll
    for (int nt = 0; nt < 4; nt++) {
      acc[0][nt] = __builtin_amdgcn_mfma_f32_16x16x32_f16(ah0, bh[nt], acc[0][nt], 0, 0, 0);
      acc[1][nt] = __builtin_amdgcn_mfma_f32_16x16x32_f16(ah1, bh[nt], acc[1][nt], 0, 0, 0);
      acc[0][nt] = __builtin_amdgcn_mfma_f32_16x16x32_f16(ah0, bl[nt], acc[0][nt], 0, 0, 0);
      acc[1][nt] = __builtin_amdgcn_mfma_f32_16x16x32_f16(ah1, bl[nt], acc[1][nt], 0, 0, 0);
      acc[0][nt] = __builtin_amdgcn_mfma_f32_16x16x32_f16(al0, bh[nt], acc[0][nt], 0, 0, 0);
      acc[1][nt] = __builtin_amdgcn_mfma_f32_16x16x32_f16(al1, bh[nt], acc[1][nt], 0, 0, 0);
    }
    if (kt < 7) {
      #pragma unroll
      for (int nt = 0; nt < 4; nt++) {
        bh[nt] = *(const half8*)(Wh + boff + (nt << 12) + (kt + 1) * 32);
        bl[nt] = *(const half8*)(Wl + boff + (nt << 12) + (kt + 1) * 32);
      }
    }
  }
}

// ---- GN(32 groups x 8 chans)+SiLU from residual regs (C-layout) -> A ----
__device__ __forceinline__ void gn_x_to_A(const float x[2][4][4],
    const float* __restrict__ gnw, const float* __restrict__ gnb,
    int col, int quad, int nb,
    _Float16* __restrict__ Ah, _Float16* __restrict__ Al) {
  #pragma unroll
  for (int nt = 0; nt < 4; nt++) {
    int n = nb + (nt << 4) + col;
    float gwv = gnw[n], gbv = gnb[n];
    #pragma unroll
    for (int mt = 0; mt < 2; mt++) {
      #pragma unroll
      for (int rg = 0; rg < 4; rg++) {
        float v = x[mt][nt][rg];
        float s = v, q = v * v;
        s += __shfl_xor(s, 1); q += __shfl_xor(q, 1);
        s += __shfl_xor(s, 2); q += __shfl_xor(q, 2);
        s += __shfl_xor(s, 4); q += __shfl_xor(q, 4);
        float mu = s * 0.125f;
        float rs = rsqrtf(q * 0.125f - mu * mu + 1e-5f);
        float y = (v - mu) * rs * gwv + gbv;
        float sv = y * sigm(y);
        hl_store(Ah, Al, ((mt << 4) + (quad << 2) + rg) * AS + n, sv);
      }
    }
  }
}

// ---- (acc + bias) -> GN+SiLU -> A, all in registers ----
__device__ __forceinline__ void epi_gn_to_A(const f32x4 acc[2][4],
    const float* __restrict__ bias,
    const float* __restrict__ gnw, const float* __restrict__ gnb,
    int col, int quad, int nb,
    _Float16* __restrict__ Ah, _Float16* __restrict__ Al) {
  #pragma unroll
  for (int nt = 0; nt < 4; nt++) {
    int n = nb + (nt << 4) + col;
    float bv = bias[n];
    float gwv = gnw[n], gbv = gnb[n];
    #pragma unroll
    for (int mt = 0; mt < 2; mt++) {
      #pragma unroll
      for (int rg = 0; rg < 4; rg++) {
        float v = acc[mt][nt][rg] + bv;
        float s = v, q = v * v;
        s += __shfl_xor(s, 1); q += __shfl_xor(q, 1);
        s += __shfl_xor(s, 2); q += __shfl_xor(q, 2);
        s += __shfl_xor(s, 4); q += __shfl_xor(q, 4);
        float mu = s * 0.125f;
        float rs = rsqrtf(q * 0.125f - mu * mu + 1e-5f);
        float y = (v - mu) * rs * gwv + gbv;
        float sv = y * sigm(y);
        hl_store(Ah, Al, ((mt << 4) + (quad << 2) + rg) * AS + n, sv);
      }
    }
  }
}

// ---- relu(acc + bias) -> A ----
__device__ __forceinline__ void epi_relu_to_A(const f32x4 acc[2][4],
    const float* __restrict__ bias, int col, int quad, int nb,
    _Float16* __restrict__ Ah, _Float16* __restrict__ Al) {
  #pragma unroll
  for (int nt = 0; nt < 4; nt++) {
    int n = nb + (nt << 4) + col;
    float bv = bias[n];
    #pragma unroll
    for (int mt = 0; mt < 2; mt++)
      #pragma unroll
      for (int rg = 0; rg < 4; rg++)
        hl_store(Ah, Al, ((mt << 4) + (quad << 2) + rg) * AS + n,
                 fmaxf(acc[mt][nt][rg] + bv, 0.f));
  }
}

__global__ __launch_bounds__(256, 3) void fused_mfma(
    const float* __restrict__ gimage, const int* __restrict__ pts,
    const float* __restrict__ gn1w, const float* __restrict__ gn1b,
    const float* __restrict__ c1b,
    const float* __restrict__ gn2w, const float* __restrict__ gn2b,
    const float* __restrict__ c2b,
    const float* __restrict__ clsw, const float* __restrict__ clsb,
    const float* __restrict__ b1, const float* __restrict__ b2,
    const float* __restrict__ w3, const float* __restrict__ b3,
    const _Float16* __restrict__ ws, float* __restrict__ out) {
  __shared__ _Float16 Ah[32 * AS];    // activation hi
  __shared__ _Float16 Al[32 * AS];    // activation lo
  __shared__ float red[4][32][4];     // head reduction scratch

  const int t = threadIdx.x;
  const int w = t >> 6;
  const int lane = t & 63;
  const int col = lane & 15;
  const int quad = lane >> 4;
  const int nb = w << 6;              // wave's 64-col slab
  const int row0 = blockIdx.x << 5;
  const int rbase = quad << 2;

  const int aoff = col * AS + (quad << 3);
  const size_t boff = (((size_t)(nb + col)) << 8) + (quad << 3);
  const _Float16* wsl = ws + NHALF;

  // ---- gather residual X directly into C-layout registers ----
  // Non-temporal: use-once scattered reads must not evict the L2-resident
  // weight planes (the B operands of all 6 GEMMs).
  float x[2][4][4];
  {
    int lin[2][4];
    #pragma unroll
    for (int mt = 0; mt < 2; mt++)
      #pragma unroll
      for (int rg = 0; rg < 4; rg++) {
        int grow = row0 + (mt << 4) + rbase + rg;
        int p0 = __builtin_nontemporal_load(pts + 2 * grow);
        int p1 = __builtin_nontemporal_load(pts + 2 * grow + 1);
        lin[mt][rg] = ((p0 >> 3) << 5) + (p1 >> 3);
      }
    const float* gbase = gimage + (((size_t)((row0 >> 11) << 8)) << 10);
    #pragma unroll
    for (int nt = 0; nt < 4; nt++) {
      const float* gc = gbase + (((size_t)(nb + (nt << 4) + col)) << 10);
      #pragma unroll
      for (int mt = 0; mt < 2; mt++)
        #pragma unroll
        for (int rg = 0; rg < 4; rg++)
          x[mt][nt][rg] = __builtin_nontemporal_load(gc + lin[mt][rg]);
    }
  }

  f32x4 acc[2][4];

  // ---- 2x ResBlock ----
  #pragma unroll 1
  for (int rb = 0; rb < 2; rb++) {
    gn_x_to_A(x, gn1w + (rb << 8), gn1b + (rb << 8), col, quad, nb, Ah, Al);
    mfma_run(acc, Ah, Al, ws + OFF_WC1 + (rb << 16), wsl + OFF_WC1 + (rb << 16),
             aoff, boff);
    __syncthreads();
    epi_gn_to_A(acc, c1b + (rb << 8), gn2w + (rb << 8), gn2b + (rb << 8),
                col, quad, nb, Ah, Al);
    mfma_run(acc, Ah, Al, ws + OFF_WC2 + (rb << 16), wsl + OFF_WC2 + (rb << 16),
             aoff, boff);
    __syncthreads();
    #pragma unroll
    for (int nt = 0; nt < 4; nt++) {
      float bv = c2b[(rb << 8) + nb + (nt << 4) + col];
      #pragma unroll
      for (int mt = 0; mt < 2; mt++)
        #pragma unroll
        for (int rg = 0; rg < 4; rg++)
          x[mt][nt][rg] += acc[mt][nt][rg] + bv;
    }
  }

  // ---- A = hl(x) for the MLP; cls partials from x (regs) ----
  #pragma unroll
  for (int nt = 0; nt < 4; nt++) {
    int n = nb + (nt << 4) + col;
    #pragma unroll
    for (int mt = 0; mt < 2; mt++)
      #pragma unroll
      for (int rg = 0; rg < 4; rg++)
        hl_store(Ah, Al, ((mt << 4) + rbase + rg) * AS + n, x[mt][nt][rg]);
  }
  {
    float pc[2][2][4];
    #pragma unroll
    for (int j = 0; j < 2; j++) {
      #pragma unroll
      for (int mt = 0; mt < 2; mt++)
        #pragma unroll
        for (int rg = 0; rg < 4; rg++)
          pc[j][mt][rg] = 0.f;
      #pragma unroll
      for (int nt = 0; nt < 4; nt++) {
        float wv = clsw[(j << 8) + nb + (nt << 4) + col];
        #pragma unroll
        for (int mt = 0; mt < 2; mt++)
          #pragma unroll
          for (int rg = 0; rg < 4; rg++)
            pc[j][mt][rg] += x[mt][nt][rg] * wv;
      }
    }
    #pragma unroll
    for (int j = 0; j < 2; j++)
      #pragma unroll
      for (int mt = 0; mt < 2; mt++)
        #pragma unroll
        for (int rg = 0; rg < 4; rg++) {
          float p = pc[j][mt][rg];
          p += __shfl_xor(p, 1);
          p += __shfl_xor(p, 2);
          p += __shfl_xor(p, 4);
          p += __shfl_xor(p, 8);
          if (col == 0) red[w][(mt << 4) + rbase + rg][j] = p;
        }
  }

  // ---- MLP gemm1 (w1); cls finalize rides alongside ----
  mfma_run(acc, Ah, Al, ws + OFF_W1, wsl + OFF_W1, aoff, boff);
  if (t < 64) {
    int r = t >> 1, j = t & 1;
    out[((size_t)(row0 + r) << 1) + j] =
        clsb[j] + red[0][r][j] + red[1][r][j] + red[2][r][j] + red[3][r][j];
  }
  __syncthreads();
  epi_relu_to_A(acc, b1, col, quad, nb, Ah, Al);

  // ---- MLP gemm2 (w2) -> relu -> w3 partials in regs ----
  mfma_run(acc, Ah, Al, ws + OFF_W2, wsl + OFF_W2, aoff, boff);
  __syncthreads();
  {
    float pb[4][2][4];
    #pragma unroll
    for (int j = 0; j < 4; j++)
      #pragma unroll
      for (int mt = 0; mt < 2; mt++)
        #pragma unroll
        for (int rg = 0; rg < 4; rg++)
          pb[j][mt][rg] = 0.f;
    #pragma unroll
    for (int nt = 0; nt < 4; nt++) {
      int n = nb + (nt << 4) + col;
      float bv = b2[n];
      float w0 = w3[n], w1v = w3[256 + n], w2v = w3[512 + n], w3v = w3[768 + n];
      #pragma unroll
      for (int mt = 0; mt < 2; mt++)
        #pragma unroll
        for (int rg = 0; rg < 4; rg++) {
          float v = fmaxf(acc[mt][nt][rg] + bv, 0.f);
          pb[0][mt][rg] += v * w0;
          pb[1][mt][rg] += v * w1v;
          pb[2][mt][rg] += v * w2v;
          pb[3][mt][rg] += v * w3v;
        }
    }
    #pragma unroll
    for (int j = 0; j < 4; j++)
      #pragma unroll
      for (int mt = 0; mt < 2; mt++)
        #pragma unroll
        for (int rg = 0; rg < 4; rg++) {
          float p = pb[j][mt][rg];
          p += __shfl_xor(p, 1);
          p += __shfl_xor(p, 2);
          p += __shfl_xor(p, 4);
          p += __shfl_xor(p, 8);
          if (col == 0) red[w][(mt << 4) + rbase + rg][j] = p;
        }
  }
  __syncthreads();
  if (t < 128) {
    int r = t >> 2, j = t & 3;
    float s = b3[j] + red[0][r][j] + red[1][r][j] + red[2][r][j] + red[3][r][j];
    out[131072 + ((size_t)(row0 + r) << 2) + j] = sigm(s);
  }
}

// ================= fp32 fallback (R11, proven) for tiny ws =================
#define LS 260
template <int EPI, bool CONV>
__device__ __forceinline__ void gemm_f32(const float* __restrict__ src,
                                         const float* __restrict__ W,
                                         const float* __restrict__ bias,
                                         float* __restrict__ dst,
                                         float* __restrict__ X) {
  const int n = threadIdx.x;
  float acc[32];
  #pragma unroll
  for (int r = 0; r < 32; r++) acc[r] = 0.f;
  #pragma unroll 1
  for (int k = 0; k < 256; k += 8) {
    float w[8];
    if (CONV) {
      #pragma unroll
      for (int j = 0; j < 8; j++) w[j] = W[(size_t)((n << 8) + k + j) * 9 + 4];
    } else {
      f32x4 wa = *(const f32x4*)(W + (n << 8) + k);
      f32x4 wb = *(const f32x4*)(W + (n << 8) + k + 4);
      w[0] = wa[0]; w[1] = wa[1]; w[2] = wa[2]; w[3] = wa[3];
      w[4] = wb[0]; w[5] = wb[1]; w[6] = wb[2]; w[7] = wb[3];
    }
    #pragma unroll
    for (int r = 0; r < 32; r++) {
      const float* xr = src + r * LS + k;
      f32x4 a0 = *(const f32x4*)xr, a1 = *(const f32x4*)(xr + 4);
      acc[r] += a0[0] * w[0] + a0[1] * w[1] + a0[2] * w[2] + a0[3] * w[3]
              + a1[0] * w[4] + a1[1] * w[5] + a1[2] * w[6] + a1[3] * w[7];
    }
  }
  float bv = bias[n];
  #pragma unroll
  for (int r = 0; r < 32; r++) {
    float v = acc[r] + bv;
    if (EPI == 0) dst[r * LS + n] = v;
    else if (EPI == 1) X[r * LS + n] += v;
    else dst[r * LS + n] = fmaxf(v, 0.f);
  }
}
__device__ __forceinline__ void gn_silu32(const float* __restrict__ src,
                                          float* __restrict__ dst,
                                          const float* __restrict__ gw,
                                          const float* __restrict__ gb, int t) {
  #pragma unroll
  for (int i = 0; i < 4; i++) {
    int task = (i << 8) + t;
    int r = task >> 5, g = task & 31;
    const float* x = src + r * LS + (g << 3);
    f32x4 x0 = *(const f32x4*)x, x1 = *(const f32x4*)(x + 4);
    float xx[8] = {x0[0], x0[1], x0[2], x0[3], x1[0], x1[1], x1[2], x1[3]};
    float s = 0.f, q = 0.f;
    #pragma unroll
    for (int j = 0; j < 8; j++) { s += xx[j]; q += xx[j] * xx[j]; }
    float mu = s * 0.125f;
    float rs = rsqrtf(q * 0.125f - mu * mu + 1e-5f);
    const float* w = gw + (g << 3);
    const float* b = gb + (g << 3);
    float* d = dst + r * LS + (g << 3);
    #pragma unroll
    for (int j = 0; j < 8; j++) {
      float y = (xx[j] - mu) * rs * w[j] + b[j];
      d[j] = y * sigm(y);
    }
  }
}
__global__ __launch_bounds__(256, 1) void fused_all(
    const float* __restrict__ gimage, const int* __restrict__ pts,
    const float* __restrict__ gn1w, const float* __restrict__ gn1b,
    const float* __restrict__ c1w, const float* __restrict__ c1b,
    const float* __restrict__ gn2w, const float* __restrict__ gn2b,
    const float* __restrict__ c2w, const float* __restrict__ c2b,
    const float* __restrict__ clsw, const float* __restrict__ clsb,
    const float* __restrict__ w1, const float* __restrict__ b1,
    const float* __restrict__ w2, const float* __restrict__ b2,
    const float* __restrict__ w3, const float* __restrict__ b3,
    float* __restrict__ out) {
  __shared__ float X[32 * LS];
  __shared__ float A[32 * LS];
  __shared__ float H[32 * LS];
  const int t = threadIdx.x;
  const int row0 = blockIdx.x << 5;
  {
    int r = t >> 3;
    int c0 = (t & 7) << 5;
    int grow = row0 + r;
    int p0 = pts[2 * grow], p1 = pts[2 * grow + 1];
    int lin = ((p0 >> 3) << 5) + (p1 >> 3);
    int b = grow >> 11;
    const float* src = gimage + (((size_t)((b << 8) + c0)) << 10) + lin;
    #pragma unroll
    for (int c = 0; c < 32; c++) X[r * LS + c0 + c] = src[(size_t)c << 10];
  }
  __syncthreads();
  #pragma unroll 1
  for (int rb = 0; rb < 2; rb++) {
    gn_silu32(X, A, gn1w + (rb << 8), gn1b + (rb << 8), t);
    __syncthreads();
    gemm_f32<0, true>(A, c1w + rb * 589824, c1b + (rb << 8), H, nullptr);
    __syncthreads();
    gn_silu32(H, A, gn2w + (rb << 8), gn2b + (rb << 8), t);
    __syncthreads();
    gemm_f32<1, true>(A, c2w + rb * 589824, c2b + (rb << 8), nullptr, X);
    __syncthreads();
  }
  if (t < 64) {
    int r = t >> 1, j = t & 1;
    float s = clsb[j];
    const float* w = clsw + (j << 8);
    const float* x = X + r * LS;
    #pragma unroll 1
    for (int k = 0; k < 256; k += 4) {
      f32x4 wv = *(const f32x4*)(w + k);
      f32x4 xv = *(const f32x4*)(x + k);
      s += xv[0] * wv[0] + xv[1] * wv[1] + xv[2] * wv[2] + xv[3] * wv[3];
    }
    out[((size_t)(row0 + r) << 1) + j] = s;
  }
  gemm_f32<2, false>(X, w1, b1, H, nullptr);
  __syncthreads();
  gemm_f32<2, false>(H, w2, b2, A, nullptr);
  __syncthreads();
  if (t < 128) {
    int r = t >> 2, j = t & 3;
    float s = b3[j];
    const float* w = w3 + (j << 8);
    const float* x = A + r * LS;
    #pragma unroll 1
    for (int k = 0; k < 256; k += 4) {
      f32x4 wv = *(const f32x4*)(w + k);
      f32x4 xv = *(const f32x4*)(x + k);
      s += xv[0] * wv[0] + xv[1] * wv[1] + xv[2] * wv[2] + xv[3] * wv[3];
    }
    out[131072 + ((size_t)(row0 + r) << 2) + j] = sigm(s);
  }
}

extern "C" void kernel_launch(void* const* d_in, const int* in_sizes, int n_in,
                              void* d_out, int out_size, void* d_ws, size_t ws_size,
                              hipStream_t stream) {
  const float* gimage = (const float*)d_in[0];
  const int* pts = (const int*)d_in[1];
  const float* gn1w = (const float*)d_in[2];
  const float* gn1b = (const float*)d_in[3];
  const float* c1w = (const float*)d_in[4];
  const float* c1b = (const float*)d_in[5];
  const float* gn2w = (const float*)d_in[6];
  const float* gn2b = (const float*)d_in[7];
  const float* c2w = (const float*)d_in[8];
  const float* c2b = (const float*)d_in[9];
  const float* clsw = (const float*)d_in[10];
  const float* clsb = (const float*)d_in[11];
  const float* w1 = (const float*)d_in[12];
  const float* b1 = (const float*)d_in[13];
  const float* w2 = (const float*)d_in[14];
  const float* b2 = (const float*)d_in[15];
  const float* w3 = (const float*)d_in[16];
  const float* b3 = (const float*)d_in[17];

  if (ws_size >= (size_t)WS_NEED) {
    _Float16* ws = (_Float16*)d_ws;
    prep<<<512, 256, 0, stream>>>(c1w, c2w, w1, w2, ws);
    fused_mfma<<<2048, 256, 0, stream>>>(gimage, pts, gn1w, gn1b, c1b,
                                         gn2w, gn2b, c2b, clsw, clsb,
                                         b1, b2, w3, b3, ws, (float*)d_out);
  } else {
    fused_all<<<2048, 256, 0, stream>>>(gimage, pts, gn1w, gn1b, c1w, c1b,
                                        gn2w, gn2b, c2w, c2b, clsw, clsb,
                                        w1, b1, w2, b2, w3, b3, (float*)d_out);
  }
}

// Round 6
// 534.328 us; speedup vs baseline: 1.2358x; 1.2148x over previous
//
#include <hip/hip_runtime.h>

// Round 20: R18-minus-NT + XCD-chunked block swizzle.
// R19 split-path failed numerics (logits 0.098 vs 0.088 thr) -> parked.
// Consolidated knowledge: R15 fused 502us proven; R16 proved pre-barrier B
// preload passes (its regression was VGPR-cap spill); R18 proved
// bounds(256,3)+preload is spill-free VGPR=84 (its regression was entirely
// the NT gather: FETCH 151->390MB). This round: that clean config + a
// bijective XCD swizzle (2048%8==0): newb=(b&7)*256+(b>>3) so each XCD's
// blocks cover 4 consecutive batches (~4MB image, ~1-2MB active) + 1.5MB
// weights -> gather AND B-loads L2-hot instead of gather thrashing all
// 32MB through each XCD L2. Arithmetic byte-identical to proven kernels
// (absmax 0.0078125). fp32 fallback (R11, proven) retained for tiny ws.

typedef __attribute__((ext_vector_type(8))) _Float16 half8;
typedef __attribute__((ext_vector_type(4))) float f32x4;

#define AS 264   // fp16 A stride (+8 pad)

#define NHALF  393216    // elements per precision plane in ws
#define OFF_WC1 0        // [2][256][256]
#define OFF_WC2 131072
#define OFF_W1  262144   // [256][256]
#define OFF_W2  327680
#define WS_NEED 1572864  // bytes = 2 planes x 393216 halves x 2B

__device__ __forceinline__ float sigm(float y) { return 1.f / (1.f + __expf(-y)); }

// ---- prep: pack weights as fp16 hi/lo planes: wsl = wsh + NHALF ----
__global__ __launch_bounds__(256) void prep(const float* __restrict__ c1w,
                                            const float* __restrict__ c2w,
                                            const float* __restrict__ w1,
                                            const float* __restrict__ w2,
                                            _Float16* __restrict__ ws) {
  int i = blockIdx.x * 256 + threadIdx.x;  // 0..131071
  {
    float v = c1w[(size_t)i * 9 + 4];
    _Float16 h = (_Float16)v;
    ws[OFF_WC1 + i] = h;
    ws[NHALF + OFF_WC1 + i] = (_Float16)(v - (float)h);
  }
  {
    float v = c2w[(size_t)i * 9 + 4];
    _Float16 h = (_Float16)v;
    ws[OFF_WC2 + i] = h;
    ws[NHALF + OFF_WC2 + i] = (_Float16)(v - (float)h);
  }
  if (i < 65536) {
    float v = w1[i];
    _Float16 h = (_Float16)v;
    ws[OFF_W1 + i] = h;
    ws[NHALF + OFF_W1 + i] = (_Float16)(v - (float)h);
    v = w2[i];
    h = (_Float16)v;
    ws[OFF_W2 + i] = h;
    ws[NHALF + OFF_W2 + i] = (_Float16)(v - (float)h);
  }
}

// ---- hi/lo split store into A planes ----
__device__ __forceinline__ void hl_store(_Float16* __restrict__ Ah,
                                         _Float16* __restrict__ Al,
                                         int idx, float v) {
  _Float16 h = (_Float16)v;
  Ah[idx] = h;
  Al[idx] = (_Float16)(v - (float)h);
}

// ---- 32x256 @ 256x256 split-fp16 MFMA: acc = Ahi*Whi + Ahi*Wlo + Alo*Whi.
// Contains its own phase barrier: the kt=0 B batch is issued BEFORE the
// barrier (B never depends on LDS), hiding L2 latency behind the barrier
// wait and the other waves' epilogue stores. Callers must NOT sync before.
__device__ __forceinline__ void mfma_run(f32x4 acc[2][4],
    const _Float16* __restrict__ Ah, const _Float16* __restrict__ Al,
    const _Float16* __restrict__ Wh, const _Float16* __restrict__ Wl,
    int aoff, size_t boff) {
  half8 bh[4], bl[4];
  #pragma unroll
  for (int nt = 0; nt < 4; nt++) {
    bh[nt] = *(const half8*)(Wh + boff + (nt << 12));
    bl[nt] = *(const half8*)(Wl + boff + (nt << 12));
  }
  #pragma unroll
  for (int mt = 0; mt < 2; mt++)
    #pragma unroll
    for (int nt = 0; nt < 4; nt++)
      acc[mt][nt] = (f32x4){0.f, 0.f, 0.f, 0.f};
  __syncthreads();
  #pragma unroll
  for (int kt = 0; kt < 8; kt++) {
    half8 ah0 = *(const half8*)(Ah + aoff + kt * 32);
    half8 ah1 = *(const half8*)(Ah + aoff + 16 * AS + kt * 32);
    half8 al0 = *(const half8*)(Al + aoff + kt * 32);
    half8 al1 = *(const half8*)(Al + aoff + 16 * AS + kt * 32);
    #pragma unroll
    for (int nt = 0; nt < 4; nt++) {
      acc[0][nt] = __builtin_amdgcn_mfma_f32_16x16x32_f16(ah0, bh[nt], acc[0][nt], 0, 0, 0);
      acc[1][nt] = __builtin_amdgcn_mfma_f32_16x16x32_f16(ah1, bh[nt], acc[1][nt], 0, 0, 0);
      acc[0][nt] = __builtin_amdgcn_mfma_f32_16x16x32_f16(ah0, bl[nt], acc[0][nt], 0, 0, 0);
      acc[1][nt] = __builtin_amdgcn_mfma_f32_16x16x32_f16(ah1, bl[nt], acc[1][nt], 0, 0, 0);
      acc[0][nt] = __builtin_amdgcn_mfma_f32_16x16x32_f16(al0, bh[nt], acc[0][nt], 0, 0, 0);
      acc[1][nt] = __builtin_amdgcn_mfma_f32_16x16x32_f16(al1, bh[nt], acc[1][nt], 0, 0, 0);
    }
    if (kt < 7) {
      #pragma unroll
      for (int nt = 0; nt < 4; nt++) {
        bh[nt] = *(const half8*)(Wh + boff + (nt << 12) + (kt + 1) * 32);
        bl[nt] = *(const half8*)(Wl + boff + (nt << 12) + (kt + 1) * 32);
      }
    }
  }
}

// ---- GN(32 groups x 8 chans)+SiLU from residual regs (C-layout) -> A ----
__device__ __forceinline__ void gn_x_to_A(const float x[2][4][4],
    const float* __restrict__ gnw, const float* __restrict__ gnb,
    int col, int quad, int nb,
    _Float16* __restrict__ Ah, _Float16* __restrict__ Al) {
  #pragma unroll
  for (int nt = 0; nt < 4; nt++) {
    int n = nb + (nt << 4) + col;
    float gwv = gnw[n], gbv = gnb[n];
    #pragma unroll
    for (int mt = 0; mt < 2; mt++) {
      #pragma unroll
      for (int rg = 0; rg < 4; rg++) {
        float v = x[mt][nt][rg];
        float s = v, q = v * v;
        s += __shfl_xor(s, 1); q += __shfl_xor(q, 1);
        s += __shfl_xor(s, 2); q += __shfl_xor(q, 2);
        s += __shfl_xor(s, 4); q += __shfl_xor(q, 4);
        float mu = s * 0.125f;
        float rs = rsqrtf(q * 0.125f - mu * mu + 1e-5f);
        float y = (v - mu) * rs * gwv + gbv;
        float sv = y * sigm(y);
        hl_store(Ah, Al, ((mt << 4) + (quad << 2) + rg) * AS + n, sv);
      }
    }
  }
}

// ---- (acc + bias) -> GN+SiLU -> A, all in registers ----
__device__ __forceinline__ void epi_gn_to_A(const f32x4 acc[2][4],
    const float* __restrict__ bias,
    const float* __restrict__ gnw, const float* __restrict__ gnb,
    int col, int quad, int nb,
    _Float16* __restrict__ Ah, _Float16* __restrict__ Al) {
  #pragma unroll
  for (int nt = 0; nt < 4; nt++) {
    int n = nb + (nt << 4) + col;
    float bv = bias[n];
    float gwv = gnw[n], gbv = gnb[n];
    #pragma unroll
    for (int mt = 0; mt < 2; mt++) {
      #pragma unroll
      for (int rg = 0; rg < 4; rg++) {
        float v = acc[mt][nt][rg] + bv;
        float s = v, q = v * v;
        s += __shfl_xor(s, 1); q += __shfl_xor(q, 1);
        s += __shfl_xor(s, 2); q += __shfl_xor(q, 2);
        s += __shfl_xor(s, 4); q += __shfl_xor(q, 4);
        float mu = s * 0.125f;
        float rs = rsqrtf(q * 0.125f - mu * mu + 1e-5f);
        float y = (v - mu) * rs * gwv + gbv;
        float sv = y * sigm(y);
        hl_store(Ah, Al, ((mt << 4) + (quad << 2) + rg) * AS + n, sv);
      }
    }
  }
}

// ---- relu(acc + bias) -> A ----
__device__ __forceinline__ void epi_relu_to_A(const f32x4 acc[2][4],
    const float* __restrict__ bias, int col, int quad, int nb,
    _Float16* __restrict__ Ah, _Float16* __restrict__ Al) {
  #pragma unroll
  for (int nt = 0; nt < 4; nt++) {
    int n = nb + (nt << 4) + col;
    float bv = bias[n];
    #pragma unroll
    for (int mt = 0; mt < 2; mt++)
      #pragma unroll
      for (int rg = 0; rg < 4; rg++)
        hl_store(Ah, Al, ((mt << 4) + (quad << 2) + rg) * AS + n,
                 fmaxf(acc[mt][nt][rg] + bv, 0.f));
  }
}

__global__ __launch_bounds__(256, 3) void fused_mfma(
    const float* __restrict__ gimage, const int* __restrict__ pts,
    const float* __restrict__ gn1w, const float* __restrict__ gn1b,
    const float* __restrict__ c1b,
    const float* __restrict__ gn2w, const float* __restrict__ gn2b,
    const float* __restrict__ c2b,
    const float* __restrict__ clsw, const float* __restrict__ clsb,
    const float* __restrict__ b1, const float* __restrict__ b2,
    const float* __restrict__ w3, const float* __restrict__ b3,
    const _Float16* __restrict__ ws, float* __restrict__ out) {
  __shared__ _Float16 Ah[32 * AS];    // activation hi
  __shared__ _Float16 Al[32 * AS];    // activation lo
  __shared__ float red[4][32][4];     // head reduction scratch

  const int t = threadIdx.x;
  const int w = t >> 6;
  const int lane = t & 63;
  const int col = lane & 15;
  const int quad = lane >> 4;
  const int nb = w << 6;              // wave's 64-col slab
  // XCD-chunked bijective swizzle (2048 % 8 == 0): blocks resident on the
  // same XCD get consecutive row ranges -> each XCD's L2 holds ~4 batches
  // of gimage + the 1.5MB weight set instead of thrashing all 32 batches.
  const int bsw = ((blockIdx.x & 7) << 8) | (blockIdx.x >> 3);
  const int row0 = bsw << 5;
  const int rbase = quad << 2;

  const int aoff = col * AS + (quad << 3);
  const size_t boff = (((size_t)(nb + col)) << 8) + (quad << 3);
  const _Float16* wsl = ws + NHALF;

  // ---- gather residual X directly into C-layout registers ----
  float x[2][4][4];
  {
    int lin[2][4];
    #pragma unroll
    for (int mt = 0; mt < 2; mt++)
      #pragma unroll
      for (int rg = 0; rg < 4; rg++) {
        int grow = row0 + (mt << 4) + rbase + rg;
        int p0 = pts[2 * grow], p1 = pts[2 * grow + 1];
        lin[mt][rg] = ((p0 >> 3) << 5) + (p1 >> 3);
      }
    const float* gbase = gimage + (((size_t)((row0 >> 11) << 8)) << 10);
    #pragma unroll
    for (int nt = 0; nt < 4; nt++) {
      const float* gc = gbase + (((size_t)(nb + (nt << 4) + col)) << 10);
      #pragma unroll
      for (int mt = 0; mt < 2; mt++)
        #pragma unroll
        for (int rg = 0; rg < 4; rg++)
          x[mt][nt][rg] = gc[lin[mt][rg]];
    }
  }

  f32x4 acc[2][4];

  // ---- 2x ResBlock ----
  #pragma unroll 1
  for (int rb = 0; rb < 2; rb++) {
    gn_x_to_A(x, gn1w + (rb << 8), gn1b + (rb << 8), col, quad, nb, Ah, Al);
    mfma_run(acc, Ah, Al, ws + OFF_WC1 + (rb << 16), wsl + OFF_WC1 + (rb << 16),
             aoff, boff);
    __syncthreads();
    epi_gn_to_A(acc, c1b + (rb << 8), gn2w + (rb << 8), gn2b + (rb << 8),
                col, quad, nb, Ah, Al);
    mfma_run(acc, Ah, Al, ws + OFF_WC2 + (rb << 16), wsl + OFF_WC2 + (rb << 16),
             aoff, boff);
    __syncthreads();
    #pragma unroll
    for (int nt = 0; nt < 4; nt++) {
      float bv = c2b[(rb << 8) + nb + (nt << 4) + col];
      #pragma unroll
      for (int mt = 0; mt < 2; mt++)
        #pragma unroll
        for (int rg = 0; rg < 4; rg++)
          x[mt][nt][rg] += acc[mt][nt][rg] + bv;
    }
  }

  // ---- A = hl(x) for the MLP; cls partials from x (regs) ----
  #pragma unroll
  for (int nt = 0; nt < 4; nt++) {
    int n = nb + (nt << 4) + col;
    #pragma unroll
    for (int mt = 0; mt < 2; mt++)
      #pragma unroll
      for (int rg = 0; rg < 4; rg++)
        hl_store(Ah, Al, ((mt << 4) + rbase + rg) * AS + n, x[mt][nt][rg]);
  }
  {
    float pc[2][2][4];
    #pragma unroll
    for (int j = 0; j < 2; j++) {
      #pragma unroll
      for (int mt = 0; mt < 2; mt++)
        #pragma unroll
        for (int rg = 0; rg < 4; rg++)
          pc[j][mt][rg] = 0.f;
      #pragma unroll
      for (int nt = 0; nt < 4; nt++) {
        float wv = clsw[(j << 8) + nb + (nt << 4) + col];
        #pragma unroll
        for (int mt = 0; mt < 2; mt++)
          #pragma unroll
          for (int rg = 0; rg < 4; rg++)
            pc[j][mt][rg] += x[mt][nt][rg] * wv;
      }
    }
    #pragma unroll
    for (int j = 0; j < 2; j++)
      #pragma unroll
      for (int mt = 0; mt < 2; mt++)
        #pragma unroll
        for (int rg = 0; rg < 4; rg++) {
          float p = pc[j][mt][rg];
          p += __shfl_xor(p, 1);
          p += __shfl_xor(p, 2);
          p += __shfl_xor(p, 4);
          p += __shfl_xor(p, 8);
          if (col == 0) red[w][(mt << 4) + rbase + rg][j] = p;
        }
  }

  // ---- MLP gemm1 (w1); cls finalize rides alongside ----
  mfma_run(acc, Ah, Al, ws + OFF_W1, wsl + OFF_W1, aoff, boff);
  if (t < 64) {
    int r = t >> 1, j = t & 1;
    out[((size_t)(row0 + r) << 1) + j] =
        clsb[j] + red[0][r][j] + red[1][r][j] + red[2][r][j] + red[3][r][j];
  }
  __syncthreads();
  epi_relu_to_A(acc, b1, col, quad, nb, Ah, Al);

  // ---- MLP gemm2 (w2) -> relu -> w3 partials in regs ----
  mfma_run(acc, Ah, Al, ws + OFF_W2, wsl + OFF_W2, aoff, boff);
  __syncthreads();
  {
    float pb[4][2][4];
    #pragma unroll
    for (int j = 0; j < 4; j++)
      #pragma unroll
      for (int mt = 0; mt < 2; mt++)
        #pragma unroll
        for (int rg = 0; rg < 4; rg++)
          pb[j][mt][rg] = 0.f;
    #pragma unroll
    for (int nt = 0; nt < 4; nt++) {
      int n = nb + (nt << 4) + col;
      float bv = b2[n];
      float w0 = w3[n], w1v = w3[256 + n], w2v = w3[512 + n], w3v = w3[768 + n];
      #pragma unroll
      for (int mt = 0; mt < 2; mt++)
        #pragma unroll
        for (int rg = 0; rg < 4; rg++) {
          float v = fmaxf(acc[mt][nt][rg] + bv, 0.f);
          pb[0][mt][rg] += v * w0;
          pb[1][mt][rg] += v * w1v;
          pb[2][mt][rg] += v * w2v;
          pb[3][mt][rg] += v * w3v;
        }
    }
    #pragma unroll
    for (int j = 0; j < 4; j++)
      #pragma unroll
      for (int mt = 0; mt < 2; mt++)
        #pragma unroll
        for (int rg = 0; rg < 4; rg++) {
          float p = pb[j][mt][rg];
          p += __shfl_xor(p, 1);
          p += __shfl_xor(p, 2);
          p += __shfl_xor(p, 4);
          p += __shfl_xor(p, 8);
          if (col == 0) red[w][(mt << 4) + rbase + rg][j] = p;
        }
  }
  __syncthreads();
  if (t < 128) {
    int r = t >> 2, j = t & 3;
    float s = b3[j] + red[0][r][j] + red[1][r][j] + red[2][r][j] + red[3][r][j];
    out[131072 + ((size_t)(row0 + r) << 2) + j] = sigm(s);
  }
}

// ================= fp32 fallback (R11, proven) for tiny ws =================
#define LS 260
template <int EPI, bool CONV>
__device__ __forceinline__ void gemm_f32(const float* __restrict__ src,
                                         const float* __restrict__ W,
                                         const float* __restrict__ bias,
                                         float* __restrict__ dst,
                                         float* __restrict__ X) {
  const int n = threadIdx.x;
  float acc[32];
  #pragma unroll
  for (int r = 0; r < 32; r++) acc[r] = 0.f;
  #pragma unroll 1
  for (int k = 0; k < 256; k += 8) {
    float w[8];
    if (CONV) {
      #pragma unroll
      for (int j = 0; j < 8; j++) w[j] = W[(size_t)((n << 8) + k + j) * 9 + 4];
    } else {
      f32x4 wa = *(const f32x4*)(W + (n << 8) + k);
      f32x4 wb = *(const f32x4*)(W + (n << 8) + k + 4);
      w[0] = wa[0]; w[1] = wa[1]; w[2] = wa[2]; w[3] = wa[3];
      w[4] = wb[0]; w[5] = wb[1]; w[6] = wb[2]; w[7] = wb[3];
    }
    #pragma unroll
    for (int r = 0; r < 32; r++) {
      const float* xr = src + r * LS + k;
      f32x4 a0 = *(const f32x4*)xr, a1 = *(const f32x4*)(xr + 4);
      acc[r] += a0[0] * w[0] + a0[1] * w[1] + a0[2] * w[2] + a0[3] * w[3]
              + a1[0] * w[4] + a1[1] * w[5] + a1[2] * w[6] + a1[7 - 7] * w[7] * 0.f
              + a1[3] * w[7];
    }
  }
  float bv = bias[n];
  #pragma unroll
  for (int r = 0; r < 32; r++) {
    float v = acc[r] + bv;
    if (EPI == 0) dst[r * LS + n] = v;
    else if (EPI == 1) X[r * LS + n] += v;
    else dst[r * LS + n] = fmaxf(v, 0.f);
  }
}
__device__ __forceinline__ void gn_silu32(const float* __restrict__ src,
                                          float* __restrict__ dst,
                                          const float* __restrict__ gw,
                                          const float* __restrict__ gb, int t) {
  #pragma unroll
  for (int i = 0; i < 4; i++) {
    int task = (i << 8) + t;
    int r = task >> 5, g = task & 31;
    const float* x = src + r * LS + (g << 3);
    f32x4 x0 = *(const f32x4*)x, x1 = *(const f32x4*)(x + 4);
    float xx[8] = {x0[0], x0[1], x0[2], x0[3], x1[0], x1[1], x1[2], x1[3]};
    float s = 0.f, q = 0.f;
    #pragma unroll
    for (int j = 0; j < 8; j++) { s += xx[j]; q += xx[j] * xx[j]; }
    float mu = s * 0.125f;
    float rs = rsqrtf(q * 0.125f - mu * mu + 1e-5f);
    const float* w = gw + (g << 3);
    const float* b = gb + (g << 3);
    float* d = dst + r * LS + (g << 3);
    #pragma unroll
    for (int j = 0; j < 8; j++) {
      float y = (xx[j] - mu) * rs * w[j] + b[j];
      d[j] = y * sigm(y);
    }
  }
}
__global__ __launch_bounds__(256, 1) void fused_all(
    const float* __restrict__ gimage, const int* __restrict__ pts,
    const float* __restrict__ gn1w, const float* __restrict__ gn1b,
    const float* __restrict__ c1w, const float* __restrict__ c1b,
    const float* __restrict__ gn2w, const float* __restrict__ gn2b,
    const float* __restrict__ c2w, const float* __restrict__ c2b,
    const float* __restrict__ clsw, const float* __restrict__ clsb,
    const float* __restrict__ w1, const float* __restrict__ b1,
    const float* __restrict__ w2, const float* __restrict__ b2,
    const float* __restrict__ w3, const float* __restrict__ b3,
    float* __restrict__ out) {
  __shared__ float X[32 * LS];
  __shared__ float A[32 * LS];
  __shared__ float H[32 * LS];
  const int t = threadIdx.x;
  const int row0 = blockIdx.x << 5;
  {
    int r = t >> 3;
    int c0 = (t & 7) << 5;
    int grow = row0 + r;
    int p0 = pts[2 * grow], p1 = pts[2 * grow + 1];
    int lin = ((p0 >> 3) << 5) + (p1 >> 3);
    int b = grow >> 11;
    const float* src = gimage + (((size_t)((b << 8) + c0)) << 10) + lin;
    #pragma unroll
    for (int c = 0; c < 32; c++) X[r * LS + c0 + c] = src[(size_t)c << 10];
  }
  __syncthreads();
  #pragma unroll 1
  for (int rb = 0; rb < 2; rb++) {
    gn_silu32(X, A, gn1w + (rb << 8), gn1b + (rb << 8), t);
    __syncthreads();
    gemm_f32<0, true>(A, c1w + rb * 589824, c1b + (rb << 8), H, nullptr);
    __syncthreads();
    gn_silu32(H, A, gn2w + (rb << 8), gn2b + (rb << 8), t);
    __syncthreads();
    gemm_f32<1, true>(A, c2w + rb * 589824, c2b + (rb << 8), nullptr, X);
    __syncthreads();
  }
  if (t < 64) {
    int r = t >> 1, j = t & 1;
    float s = clsb[j];
    const float* w = clsw + (j << 8);
    const float* x = X + r * LS;
    #pragma unroll 1
    for (int k = 0; k < 256; k += 4) {
      f32x4 wv = *(const f32x4*)(w + k);
      f32x4 xv = *(const f32x4*)(x + k);
      s += xv[0] * wv[0] + xv[1] * wv[1] + xv[2] * wv[2] + xv[3] * wv[3];
    }
    out[((size_t)(row0 + r) << 1) + j] = s;
  }
  gemm_f32<2, false>(X, w1, b1, H, nullptr);
  __syncthreads();
  gemm_f32<2, false>(H, w2, b2, A, nullptr);
  __syncthreads();
  if (t < 128) {
    int r = t >> 2, j = t & 3;
    float s = b3[j];
    const float* w = w3 + (j << 8);
    const float* x = A + r * LS;
    #pragma unroll 1
    for (int k = 0; k < 256; k += 4) {
      f32x4 wv = *(const f32x4*)(w + k);
      f32x4 xv = *(const f32x4*)(x + k);
      s += xv[0] * wv[0] + xv[1] * wv[1] + xv[2] * wv[2] + xv[3] * wv[3];
    }
    out[131072 + ((size_t)(row0 + r) << 2) + j] = sigm(s);
  }
}

extern "C" void kernel_launch(void* const* d_in, const int* in_sizes, int n_in,
                              void* d_out, int out_size, void* d_ws, size_t ws_size,
                              hipStream_t stream) {
  const float* gimage = (const float*)d_in[0];
  const int* pts = (const int*)d_in[1];
  const float* gn1w = (const float*)d_in[2];
  const float* gn1b = (const float*)d_in[3];
  const float* c1w = (const float*)d_in[4];
  const float* c1b = (const float*)d_in[5];
  const float* gn2w = (const float*)d_in[6];
  const float* gn2b = (const float*)d_in[7];
  const float* c2w = (const float*)d_in[8];
  const float* c2b = (const float*)d_in[9];
  const float* clsw = (const float*)d_in[10];
  const float* clsb = (const float*)d_in[11];
  const float* w1 = (const float*)d_in[12];
  const float* b1 = (const float*)d_in[13];
  const float* w2 = (const float*)d_in[14];
  const float* b2 = (const float*)d_in[15];
  const float* w3 = (const float*)d_in[16];
  const float* b3 = (const float*)d_in[17];

  if (ws_size >= (size_t)WS_NEED) {
    _Float16* ws = (_Float16*)d_ws;
    prep<<<512, 256, 0, stream>>>(c1w, c2w, w1, w2, ws);
    fused_mfma<<<2048, 256, 0, stream>>>(gimage, pts, gn1w, gn1b, c1b,
                                         gn2w, gn2b, c2b, clsw, clsb,
                                         b1, b2, w3, b3, ws, (float*)d_out);
  } else {
    fused_all<<<2048, 256, 0, stream>>>(gimage, pts, gn1w, gn1b, c1w, c1b,
                                        gn2w, gn2b, c2w, c2b, clsw, clsb,
                                        w1, b1, w2, b2, w3, b3, (float*)d_out);
  }
}